// Round 6
// baseline (57.718 us; speedup 1.0000x reference)
//
#include <hip/hip_runtime.h>
#include <hip/hip_bf16.h>
#include <math.h>

// Problem constants
#define BB 8
#define SS 2048
#define DD 768
#define NPOS 512
#define TC 64                 // t-chunks for ctx atomic accumulation (32 t each)
#define DSPLIT 16             // d-splits for the q@W mini-GEMM (R2-proven)
#define DCHUNK (DD / DSPLIT)  // 48
#define ETOT (DD + NPOS)      // 1280
#define SCALE 0.036084391824351615    // 1/sqrt(768) (double)

// Workspace layout (float offsets, 16B-aligned)
#define WS_Q      0        // 6144
#define WS_QK     6144     // 6144
#define WS_LI     12288    // 4096
#define WS_QBK    16384    // 16
#define WS_LOGITS 16400    // 16384
#define WS_ATTN   32784    // 16384
#define WS_CTX    49168    // 6144 (atomic-accumulated, zeroed in k_q)
#define WS_PWS    55312    // DOUBLE array: DSPLIT*BB*ETOT = 163840 doubles (byte 221248, 8B-aligned)

__device__ __forceinline__ float wave_sum(float v) {
    #pragma unroll
    for (int off = 32; off > 0; off >>= 1) v += __shfl_xor(v, off, 64);
    return v;
}

// q[b,d] = x[b,0,:].Wq[d,:] + bq[d]; wave per output; double per-lane accum.
// Also zeros ctx (6144 floats) for the later atomic accumulation.
__global__ __launch_bounds__(256) void k_q(const float* __restrict__ x,
        const float* __restrict__ Wq, const float* __restrict__ bq,
        float* __restrict__ q, float* __restrict__ ctx) {
    int zi = blockIdx.x * 256 + threadIdx.x;
    if (zi < BB * DD) ctx[zi] = 0.f;
    int gw = zi >> 6;
    int lane = threadIdx.x & 63;
    if (gw >= BB * DD) return;
    int b = gw / DD, d = gw % DD;
    const float4* vr = (const float4*)(x + (size_t)b * SS * DD);
    const float4* wr = (const float4*)(Wq + (size_t)d * DD);
    double acc = 0.0;
    #pragma unroll
    for (int j = 0; j < 3; ++j) {
        float4 a = vr[lane + 64 * j];
        float4 w = wr[lane + 64 * j];
        acc += (double)a.x * w.x + (double)a.y * w.y
             + (double)a.z * w.z + (double)a.w * w.w;
    }
    float accf = wave_sum((float)acc);
    if (lane == 0) q[gw] = accf + bq[d];
}

// Partial q@[Wk | pos_emb] -> pws (double, deterministic). Block (0,0) also qbk.
// grid (5, DSPLIT): x 0..2 -> Wk e-chunks of 256; 3..4 -> pos_emb chunks.
__global__ __launch_bounds__(256) void k_qkw(const float* __restrict__ q,
        const float* __restrict__ Wk, const float* __restrict__ pos_emb,
        const float* __restrict__ bk,
        double* __restrict__ pws, float* __restrict__ qbk) {
    int part = blockIdx.x, ds = blockIdx.y, tid = threadIdx.x;
    __shared__ float qs[BB][DCHUNK];
    for (int i = tid; i < BB * DCHUNK; i += 256) {
        int b = i / DCHUNK, d = i % DCHUNK;
        qs[b][d] = q[b * DD + ds * DCHUNK + d];
    }
    __syncthreads();
    const float* Wsrc; int stride, eg;
    if (part < 3) { Wsrc = Wk; stride = DD; eg = part * 256 + tid; }
    else { Wsrc = pos_emb; stride = NPOS; eg = DD + (part - 3) * 256 + tid; }
    int e = (part < 3) ? eg : eg - DD;
    const float* col = Wsrc + (size_t)(ds * DCHUNK) * stride + e;
    double acc[BB];
    #pragma unroll
    for (int b = 0; b < BB; ++b) acc[b] = 0.0;
    #pragma unroll 4
    for (int d = 0; d < DCHUNK; ++d) {
        double w = (double)col[(size_t)d * stride];
        #pragma unroll
        for (int b = 0; b < BB; ++b) acc[b] += (double)qs[b][d] * w;
    }
    #pragma unroll
    for (int b = 0; b < BB; ++b)
        pws[((size_t)ds * BB + b) * ETOT + eg] = acc[b];
    // qbk[b] = q[b,:].bk — one block, 4 waves x 2 batches
    if (part == 0 && ds == 0) {
        int w = tid >> 6, lane = tid & 63;
        #pragma unroll
        for (int r = 0; r < 2; ++r) {
            int b = w + 4 * r;
            double p = 0.0;
            #pragma unroll
            for (int j = 0; j < 12; ++j)
                p += (double)q[b * DD + lane + 64 * j] * (double)bk[lane + 64 * j];
            float pf = wave_sum((float)p);
            if (lane == 0) qbk[b] = pf;
        }
    }
}

// Reduce DSPLIT double partials -> qk[b,0:768], lint[b,0:512] (deterministic order)
__global__ __launch_bounds__(256) void k_qkr(const double* __restrict__ pws,
        float* __restrict__ qk, float* __restrict__ lint) {
    int idx = blockIdx.x * 256 + threadIdx.x;   // 0 .. 10239
    if (idx >= BB * ETOT) return;
    int b = idx / ETOT, e = idx % ETOT;
    double acc = 0.0;
    #pragma unroll 4
    for (int ds = 0; ds < DSPLIT; ++ds)
        acc += pws[((size_t)ds * BB + b) * ETOT + e];
    if (e < DD) qk[b * DD + e] = (float)acc;
    else lint[b * NPOS + (e - DD)] = (float)acc;
}

// logits[b,t] = scale * (x[b,t,:].qk[b,:] + qbk[b]); masked -> -inf. Wave per row.
__global__ __launch_bounds__(256) void k_logits(const float* __restrict__ x,
        const float* __restrict__ qk, const float* __restrict__ qbk,
        const int* __restrict__ mask, float* __restrict__ logits) {
    int gw = (blockIdx.x * 256 + threadIdx.x) >> 6;
    int lane = threadIdx.x & 63;
    if (gw >= BB * SS) return;
    int b = gw >> 11;
    const float4* xr = (const float4*)(x + (size_t)gw * DD);
    const float4* wr = (const float4*)(qk + (size_t)b * DD);
    double acc = 0.0;
    #pragma unroll
    for (int j = 0; j < 3; ++j) {
        float4 a = xr[lane + 64 * j];
        float4 w = wr[lane + 64 * j];
        acc += (double)a.x * w.x + (double)a.y * w.y
             + (double)a.z * w.z + (double)a.w * w.w;
    }
    float accf = wave_sum((float)acc);
    if (lane == 0) {
        float lg = (float)(((double)accf + (double)qbk[b]) * SCALE);
        logits[gw] = mask[gw] ? lg : -INFINITY;
    }
}

// Per batch: sigmoid gates, suffix-cumsum (double), CoPE interp, softmax -> attn.
// R2-proven structure: 256 threads, 8 t per thread, LDS Hillis-Steele scan.
__global__ __launch_bounds__(256) void k_scan(const float* __restrict__ logits,
        const float* __restrict__ lint, float* __restrict__ attn) {
    int b = blockIdx.x, tid = threadIdx.x;
    __shared__ float lg[SS];
    __shared__ float li[NPOS];
    __shared__ double sa[256], sb[256];
    for (int i = tid; i < SS; i += 256) lg[i] = logits[b * SS + i];
    for (int i = tid; i < NPOS; i += 256) li[i] = lint[b * NPOS + i];
    __syncthreads();
    int base = tid * 8;
    double loc[8];
    double run = 0.0;
    #pragma unroll
    for (int k = 7; k >= 0; --k) {              // suffix sum within own chunk
        double v = (double)lg[base + k];
        double gk = 1.0 / (1.0 + exp(-v));      // sigmoid; -inf -> 0
        run += gk;
        loc[k] = run;
    }
    sa[tid] = run;
    __syncthreads();
    // Hillis-Steele inclusive SUFFIX scan over 256 chunk totals (double, ping-pong)
    double* src = sa; double* dst = sb;
    for (int off = 1; off < 256; off <<= 1) {
        double v = src[tid];
        if (tid + off < 256) v += src[tid + off];
        dst[tid] = v;
        __syncthreads();
        double* t_ = src; src = dst; dst = t_;
    }
    double st = (tid < 255) ? src[tid + 1] : 0.0;  // exclusive suffix of later chunks
    // CoPE-adjusted logits (interp in double)
    float adj[8];
    float m = -INFINITY;
    #pragma unroll
    for (int k = 0; k < 8; ++k) {
        float val = lg[base + k];
        float nv;
        if (val == -INFINITY) {
            nv = val;                            // masked stays -inf
        } else {
            double p = fmin(loc[k] + st, (double)(NPOS - 1));
            double pf = floor(p);
            double wt = p - pf;
            int fi = (int)pf;
            int ci = (int)ceil(p);
            nv = (float)((double)val + (double)li[ci] * wt + (double)li[fi] * (1.0 - wt));
        }
        adj[k] = nv;
        m = fmaxf(m, nv);
    }
    __syncthreads();            // st reads of sa/sb done; safe to reuse
    sa[tid] = (double)m;
    __syncthreads();
    for (int s2 = 128; s2 > 0; s2 >>= 1) {
        if (tid < s2) sa[tid] = fmax(sa[tid], sa[tid + s2]);
        __syncthreads();
    }
    float bm = (float)sa[0];
    __syncthreads();
    float sum = 0.f;
    #pragma unroll
    for (int k = 0; k < 8; ++k) { adj[k] = expf(adj[k] - bm); sum += adj[k]; }
    sa[tid] = (double)sum;
    __syncthreads();
    for (int s2 = 128; s2 > 0; s2 >>= 1) {
        if (tid < s2) sa[tid] += sa[tid + s2];
        __syncthreads();
    }
    float inv = 1.f / (float)sa[0];
    float4* out4 = (float4*)(attn + b * SS + base);
    out4[0] = make_float4(adj[0] * inv, adj[1] * inv, adj[2] * inv, adj[3] * inv);
    out4[1] = make_float4(adj[4] * inv, adj[5] * inv, adj[6] * inv, adj[7] * inv);
}

// attn-weighted row sums, atomic-accumulated into ctx (linear path — reorder-safe).
__global__ __launch_bounds__(192) void k_ctx(const float* __restrict__ x,
        const float* __restrict__ attn, float* __restrict__ ctx) {
    int tc = blockIdx.x, b = blockIdx.y, tid = threadIdx.x;
    const int TPC = SS / TC;  // 32
    float4 acc = make_float4(0.f, 0.f, 0.f, 0.f);
    const float4* xr = (const float4*)(x + ((size_t)b * SS + (size_t)tc * TPC) * DD);
    const float* at = attn + b * SS + tc * TPC;
    for (int i = 0; i < TPC; ++i) {
        float a = at[i];
        float4 xv = xr[(size_t)i * 192 + tid];
        acc.x += a * xv.x; acc.y += a * xv.y; acc.z += a * xv.z; acc.w += a * xv.w;
    }
    float* dst = ctx + b * DD + tid * 4;
    atomicAdd(dst + 0, acc.x);
    atomicAdd(dst + 1, acc.y);
    atomicAdd(dst + 2, acc.z);
    atomicAdd(dst + 3, acc.w);
}

// out[b,d] = ctx[b,:].Wv[d,:] + bv[d]; wave per output, double per-lane accum.
__global__ __launch_bounds__(256) void k_out(const float* __restrict__ ctx,
        const float* __restrict__ Wv, const float* __restrict__ bv,
        float* __restrict__ out) {
    int gw = (blockIdx.x * 256 + threadIdx.x) >> 6;
    int lane = threadIdx.x & 63;
    if (gw >= BB * DD) return;
    int b = gw / DD, d = gw % DD;
    const float4* vr = (const float4*)(ctx + (size_t)b * DD);
    const float4* wr = (const float4*)(Wv + (size_t)d * DD);
    double acc = 0.0;
    #pragma unroll
    for (int j = 0; j < 3; ++j) {
        float4 a = vr[lane + 64 * j];
        float4 w = wr[lane + 64 * j];
        acc += (double)a.x * w.x + (double)a.y * w.y
             + (double)a.z * w.z + (double)a.w * w.w;
    }
    float accf = wave_sum((float)acc);
    if (lane == 0) out[gw] = accf + bv[d];
}

extern "C" void kernel_launch(void* const* d_in, const int* in_sizes, int n_in,
                              void* d_out, int out_size, void* d_ws, size_t ws_size,
                              hipStream_t stream) {
    const float* x       = (const float*)d_in[0];  // [B,S,D]
    const int*   mask    = (const int*)  d_in[1];  // [B,S]
    const float* Wq      = (const float*)d_in[2];
    const float* bq      = (const float*)d_in[3];
    const float* Wk      = (const float*)d_in[4];
    const float* bk      = (const float*)d_in[5];
    const float* Wv      = (const float*)d_in[6];
    const float* bv      = (const float*)d_in[7];
    const float* pos_emb = (const float*)d_in[8];  // [D,NPOS]
    float* out = (float*)d_out;                    // [B,D]

    float*  ws     = (float*)d_ws;
    float*  q      = ws + WS_Q;
    float*  qk     = ws + WS_QK;
    float*  lint   = ws + WS_LI;
    float*  qbk    = ws + WS_QBK;
    float*  logits = ws + WS_LOGITS;
    float*  attn   = ws + WS_ATTN;
    float*  ctx    = ws + WS_CTX;
    double* pws    = (double*)(ws + WS_PWS);

    // 1. q from row s=0 (double accum); zero ctx
    k_q<<<dim3((BB * DD) / 4), dim3(256), 0, stream>>>(x, Wq, bq, q, ctx);
    // 2. q @ [Wk | pos_emb] -> double partials (deterministic); qbk
    k_qkw<<<dim3(5, DSPLIT), dim3(256), 0, stream>>>(q, Wk, pos_emb, bk, pws, qbk);
    // 3. reduce partials -> qk, lint
    k_qkr<<<dim3((BB * ETOT + 255) / 256), dim3(256), 0, stream>>>(pws, qk, lint);
    // 4. logits (pass 1 over x, 50 MB; double accum)
    k_logits<<<dim3((BB * SS) / 4), dim3(256), 0, stream>>>(x, qk, qbk, mask, logits);
    // 5. CoPE scan (double) + softmax -> attn
    k_scan<<<dim3(BB), dim3(256), 0, stream>>>(logits, lint, attn);
    // 6. ctx = attn-weighted row sums (pass 2 over x, atomic)
    k_ctx<<<dim3(TC, BB), dim3(192), 0, stream>>>(x, attn, ctx);
    // 7. out = ctx @ Wv.T + bv
    k_out<<<dim3((BB * DD) / 4), dim3(256), 0, stream>>>(ctx, Wv, bv, out);
}